// Round 12
// baseline (699.719 us; speedup 1.0000x reference)
//
#include <hip/hip_runtime.h>
#include <hip/hip_cooperative_groups.h>

namespace cg = cooperative_groups;

#define N1 1000000
#define N2 131072
#define N3 16384
#define N4 2048
#define N5 256
#define C 48
#define CAP 48   // max rows per segment; P(Binomial(1M,1/131072) >= 48) ~ 1e-17

// ------------------------------------------------------- per-row argmax
__device__ __forceinline__ int argmax48(const float4* __restrict__ row) {
    float best = -__builtin_inff();
    int bi = 0;
#pragma unroll
    for (int i = 0; i < 12; ++i) {
        float4 v = row[i];
        if (v.x > best) { best = v.x; bi = 4 * i + 0; }
        if (v.y > best) { best = v.y; bi = 4 * i + 1; }
        if (v.z > best) { best = v.z; bi = 4 * i + 2; }
        if (v.w > best) { best = v.w; bi = 4 * i + 3; }
    }
    return bi;
}

// One cooperative kernel, all six phases separated by grid.sync():
// P0 zero | P1 slot-sort | P2 segsum+argmax+f3 | P3 level3 | P4 level4 | P5 final
__global__ void __launch_bounds__(256, 8)
mega_kernel(const float* __restrict__ slabel,
            const int* __restrict__ parent2,
            const int* __restrict__ parent3,
            const int* __restrict__ parent4,
            const int* __restrict__ parent5,
            const int4* __restrict__ idx2,
            const int4* __restrict__ idx3,
            const int4* __restrict__ idx4,
            const int4* __restrict__ idx5,
            int4* __restrict__ out,
            float* __restrict__ ws) {
    cg::grid_group grid = cg::this_grid();
    const int tid = blockIdx.x * 256 + threadIdx.x;
    const int nth = gridDim.x * 256;

    // ws layout (dwords): [f3 | f4 | f5 | cnt2 | rowid2(N2*CAP)] then tabs (bytes)
    float* f3 = ws;
    float* f4 = f3 + N3 * C;
    float* f5 = f4 + N4 * C;
    int* cnt2 = (int*)(f5 + N5 * C);
    int* rowid2 = cnt2 + N2;
    unsigned char* tab2 = (unsigned char*)(rowid2 + N2 * CAP);
    unsigned char* tab3 = tab2 + N2;
    unsigned char* tab4 = tab3 + N3;

    // ---- P0: zero f3|f4|f5|cnt2 (ws poisoned between calls)
    const int ZF4 = ((N3 + N4 + N5) * C + N2) / 4;   // 257,024 float4
    const float4 z4 = make_float4(0.f, 0.f, 0.f, 0.f);
    for (int i = tid; i < ZF4; i += nth) ((float4*)ws)[i] = z4;
    grid.sync();

    // ---- P1: direct-slot counting sort (int4-vectorized parent reads)
    for (int i = tid; i < N1 / 4; i += nth) {
        int4 p4 = ((const int4*)parent2)[i];
        int b = 4 * i;
        int s;
        s = atomicAdd(&cnt2[p4.x], 1); if (s < CAP) rowid2[p4.x * CAP + s] = b;
        s = atomicAdd(&cnt2[p4.y], 1); if (s < CAP) rowid2[p4.y * CAP + s] = b + 1;
        s = atomicAdd(&cnt2[p4.z], 1); if (s < CAP) rowid2[p4.z * CAP + s] = b + 2;
        s = atomicAdd(&cnt2[p4.w], 1); if (s < CAP) rowid2[p4.w * CAP + s] = b + 3;
    }
    grid.sync();

    // ---- P2: fused segment-sum (5 rows per load instruction, 3 bursts) +
    //          contiguous 48-lane f3 atomic + wave argmax -> tab2
    {
        const int gw = tid >> 6, lane = tid & 63, gnw = nth >> 6;
        const int g = lane / 12;                 // row-group 0..4 (lanes 60-63 idle)
        const int c4 = lane - g * 12;            // channel quad 0..11
        const bool act = (lane < 60);
        const bool ch = (lane < C);
        for (int seg = gw; seg < N2; seg += gnw) {
            int n = cnt2[seg];
            if (n > CAP) n = CAP;                // safety clamp (never hit)
            int rv = (lane < n) ? rowid2[seg * CAP + lane] : 0;
            float4 acc = make_float4(0.f, 0.f, 0.f, 0.f);
            for (int k = 0; k < n; k += 15) {    // three 5-row bursts in flight
                int r0 = __shfl(rv, k + g);
                int r1 = __shfl(rv, k + 5 + g);
                int r2 = __shfl(rv, k + 10 + g);
                bool p0 = act && (k + g < n);
                bool p1 = act && (k + 5 + g < n);
                bool p2 = act && (k + 10 + g < n);
                float4 v0 = p0 ? *(const float4*)(slabel + (size_t)r0 * C + c4 * 4)
                               : make_float4(0.f, 0.f, 0.f, 0.f);
                float4 v1 = p1 ? *(const float4*)(slabel + (size_t)r1 * C + c4 * 4)
                               : make_float4(0.f, 0.f, 0.f, 0.f);
                float4 v2 = p2 ? *(const float4*)(slabel + (size_t)r2 * C + c4 * 4)
                               : make_float4(0.f, 0.f, 0.f, 0.f);
                acc.x += v0.x + v1.x + v2.x;
                acc.y += v0.y + v1.y + v2.y;
                acc.z += v0.z + v1.z + v2.z;
                acc.w += v0.w + v1.w + v2.w;
            }
            // reduce across the 5 row-groups (valid on lanes 0..11)
            float4 tot = acc;
#pragma unroll
            for (int gg = 1; gg < 5; ++gg) {
                int sl = c4 + 12 * gg;
                tot.x += __shfl(acc.x, sl);
                tot.y += __shfl(acc.y, sl);
                tot.z += __shfl(acc.z, sl);
                tot.w += __shfl(acc.w, sl);
            }
            // redistribute: lane l (0..47) takes comp l%4 of quad l/4
            int q = lane >> 2;
            float vx = __shfl(tot.x, q);
            float vy = __shfl(tot.y, q);
            float vz = __shfl(tot.z, q);
            float vw = __shfl(tot.w, q);
            int m = lane & 3;
            float val = (m == 0) ? vx : (m == 1) ? vy : (m == 2) ? vz : vw;
            // ONE contiguous 48-lane atomic into f3
            int p3 = parent3[seg];
            if (ch) atomicAdd(&f3[(size_t)p3 * C + lane], val);
            // wave argmax (first-max tie-break: smaller index)
            float bv = ch ? val : -__builtin_inff();
            int bi = ch ? lane : 0x7fffffff;
#pragma unroll
            for (int d = 32; d > 0; d >>= 1) {
                float ov = __shfl_xor(bv, d);
                int oi = __shfl_xor(bi, d);
                if (ov > bv || (ov == bv && oi < bi)) { bv = ov; bi = oi; }
            }
            if (lane == 0) tab2[seg] = (unsigned char)bi;
        }
    }
    grid.sync();

    // ---- P3: level 3 (f3 -> f4 atomics + tab3 argmax)
    const int T3 = N3 * C;
    for (int i = tid; i < T3 + N3; i += nth) {
        if (i < T3) {
            unsigned r = (unsigned)i / C;
            unsigned c = (unsigned)i - r * C;
            atomicAdd(&f4[(unsigned)parent4[r] * C + c], f3[i]);
        } else {
            int r = i - T3;
            tab3[r] = (unsigned char)argmax48((const float4*)f3 + r * 12);
        }
    }
    grid.sync();

    // ---- P4: level 4 (f4 -> f5 atomics + tab4 argmax)
    const int T4 = N4 * C;
    for (int i = tid; i < T4 + N4; i += nth) {
        if (i < T4) {
            unsigned r = (unsigned)i / C;
            unsigned c = (unsigned)i - r * C;
            atomicAdd(&f5[(unsigned)parent5[r] * C + c], f4[i]);
        } else {
            int r = i - T4;
            tab4[r] = (unsigned char)argmax48((const float4*)f4 + r * 12);
        }
    }
    grid.sync();

    // ---- P5: final gather (tab lookups + per-block LDS tab5)
    __shared__ unsigned char t5[N5];
    t5[threadIdx.x] = (unsigned char)argmax48((const float4*)f5 + threadIdx.x * 12);
    __syncthreads();
    const int NQ = N1 / 4;
    for (int t = tid; t < NQ; t += nth) {
        int4 a = idx2[t], b = idx3[t], c = idx4[t], d = idx5[t];
        out[t]          = make_int4(tab2[a.x], tab2[a.y], tab2[a.z], tab2[a.w]);
        out[NQ + t]     = make_int4(tab3[b.x], tab3[b.y], tab3[b.z], tab3[b.w]);
        out[2 * NQ + t] = make_int4(tab4[c.x], tab4[c.y], tab4[c.z], tab4[c.w]);
        out[3 * NQ + t] = make_int4(t5[d.x], t5[d.y], t5[d.z], t5[d.w]);
    }
}

extern "C" void kernel_launch(void* const* d_in, const int* in_sizes, int n_in,
                              void* d_out, int out_size, void* d_ws, size_t ws_size,
                              hipStream_t stream) {
    const float* slabel = (const float*)d_in[0];
    const int* parent2  = (const int*)d_in[1];
    const int* parent3  = (const int*)d_in[2];
    const int* parent4  = (const int*)d_in[3];
    const int* parent5  = (const int*)d_in[4];
    const int4* idx2    = (const int4*)d_in[5];
    const int4* idx3    = (const int4*)d_in[6];
    const int4* idx4    = (const int4*)d_in[7];
    const int4* idx5    = (const int4*)d_in[8];
    int4* out = (int4*)d_out;        // JAX argmax output dtype is int32
    float* ws = (float*)d_ws;

    // grid must satisfy the cooperative-launch residency constraint:
    // query achievable blocks/CU (host-side, capture-safe) and clamp.
    int maxB = 8;
    (void)hipOccupancyMaxActiveBlocksPerMultiprocessor(
        &maxB, reinterpret_cast<const void*>(mega_kernel), 256, 0);
    if (maxB < 1) maxB = 1;
    int grid = maxB * 256;           // 256 CUs on MI355X
    if (grid > 2048) grid = 2048;    // 8 blocks/CU cap (32 waves/CU)

    void* args[] = { (void*)&slabel, (void*)&parent2, (void*)&parent3,
                     (void*)&parent4, (void*)&parent5,
                     (void*)&idx2, (void*)&idx3, (void*)&idx4, (void*)&idx5,
                     (void*)&out, (void*)&ws };
    (void)hipLaunchCooperativeKernel(reinterpret_cast<const void*>(mega_kernel),
                                     dim3(grid), dim3(256), args, 0, stream);
}

// Round 13
// 162.539 us; speedup vs baseline: 4.3049x; 4.3049x over previous
//
#include <hip/hip_runtime.h>

#define N1 1000000
#define N2 131072
#define N3 16384
#define N4 2048
#define N5 256
#define C 48
#define CAP 48   // max rows per segment; P(Binomial(1M,1/131072) >= 48) ~ 1e-17

// ---------- reorder + table zeroing fused (disjoint buffers, one dispatch)
// blocks [0, ZBLK): zero f3|f4|f5 ; blocks [ZBLK, ...): direct-slot sort
#define ZDW ((N3 + N4 + N5) * C)        // 897,024 dwords to zero
#define ZF4 (ZDW / 4)                    // 224,256 float4
#define ZBLK ((ZF4 + 255) / 256)         // 876 zero blocks
__global__ void reorder_zero_kernel(const int* __restrict__ parent,
                                    int* __restrict__ cnt,
                                    int* __restrict__ rowid,
                                    float4* __restrict__ ftab) {
    if ((int)blockIdx.x < ZBLK) {
        int i = blockIdx.x * 256 + threadIdx.x;
        if (i < ZF4) ftab[i] = make_float4(0.f, 0.f, 0.f, 0.f);
        return;
    }
    int i = ((int)blockIdx.x - ZBLK) * 256 + threadIdx.x;
    if (i >= N1) return;
    int p = parent[i];
    int s = atomicAdd(&cnt[p], 1);
    if (s < CAP) rowid[p * CAP + s] = i;
}

// --------------------- fused: segment-sum + row-argmax + f3 accumulation
// One 64-lane wave per segment. Load phase: lane l = (group g=l/12, quad
// c4=l%12) loads float4 of channels [4*c4,4*c4+3] of row (k+g) -> each
// load instruction fetches FIVE random rows; 3 bursts = 15 rows/iter.
// rowid read: lanes 0-15 only (ONE 64B line; covers n<=16 = 98.7% of
// segments); wave-uniform fallback reads lanes 16-47 when n>16.
// Epilogue: reduce 5 groups (16 shfl), redistribute to 48 contiguous
// lanes (4 shfl) -> ONE contiguous 48-lane atomicAdd + argmax butterfly.
__global__ void segsum_fused_kernel(const float* __restrict__ src,
                                    const int* __restrict__ rowid,
                                    const int* __restrict__ cnt,
                                    const int* __restrict__ parent3,
                                    float* __restrict__ f3,
                                    unsigned char* __restrict__ tab2, int nseg) {
    int wid = threadIdx.x >> 6;
    int lane = threadIdx.x & 63;
    int seg = blockIdx.x * 4 + wid;
    if (seg >= nseg) return;
    int n = cnt[seg];
    if (n > CAP) n = CAP;                       // safety clamp (never hit)
    int rv = (lane < 16 && lane < n) ? rowid[seg * CAP + lane] : 0;
    if (n > 16) {                               // rare (~1.3%), wave-uniform
        if (lane >= 16 && lane < n) rv = rowid[seg * CAP + lane];
    }
    int g = lane / 12;                          // 0..4 active, 5 = lanes 60-63
    int c4 = lane - g * 12;                     // 0..11
    const bool act = (lane < 60);
    float4 acc = make_float4(0.f, 0.f, 0.f, 0.f);
    for (int k = 0; k < n; k += 15) {           // three 5-row bursts in flight
        int r0 = __shfl(rv, k + g);
        int r1 = __shfl(rv, k + 5 + g);
        int r2 = __shfl(rv, k + 10 + g);
        bool p0 = act && (k + g < n);
        bool p1 = act && (k + 5 + g < n);
        bool p2 = act && (k + 10 + g < n);
        float4 v0 = p0 ? *(const float4*)(src + (size_t)r0 * C + c4 * 4)
                       : make_float4(0.f, 0.f, 0.f, 0.f);
        float4 v1 = p1 ? *(const float4*)(src + (size_t)r1 * C + c4 * 4)
                       : make_float4(0.f, 0.f, 0.f, 0.f);
        float4 v2 = p2 ? *(const float4*)(src + (size_t)r2 * C + c4 * 4)
                       : make_float4(0.f, 0.f, 0.f, 0.f);
        acc.x += v0.x + v1.x + v2.x;
        acc.y += v0.y + v1.y + v2.y;
        acc.z += v0.z + v1.z + v2.z;
        acc.w += v0.w + v1.w + v2.w;
    }
    // ---- reduce across the 5 row-groups (valid on lanes 0..11)
    float4 tot = acc;
#pragma unroll
    for (int gg = 1; gg < 5; ++gg) {
        int sl = c4 + 12 * gg;
        tot.x += __shfl(acc.x, sl);
        tot.y += __shfl(acc.y, sl);
        tot.z += __shfl(acc.z, sl);
        tot.w += __shfl(acc.w, sl);
    }
    // ---- redistribute: lane l (0..47) takes channel l = comp l%4 of quad l/4
    int q = lane >> 2;
    float vx = __shfl(tot.x, q);
    float vy = __shfl(tot.y, q);
    float vz = __shfl(tot.z, q);
    float vw = __shfl(tot.w, q);
    int m = lane & 3;
    float val = (m == 0) ? vx : (m == 1) ? vy : (m == 2) ? vz : vw;
    // ---- ONE contiguous 48-lane atomic into f3
    int p3 = parent3[seg];
    const bool ch = (lane < C);
    if (ch) atomicAdd(&f3[(size_t)p3 * C + lane], val);
    // ---- wave argmax of the f2 row (first-max tie-break: smaller index)
    float bv = ch ? val : -__builtin_inff();
    int bi = ch ? lane : 0x7fffffff;
#pragma unroll
    for (int d = 32; d > 0; d >>= 1) {
        float ov = __shfl_xor(bv, d);
        int oi = __shfl_xor(bi, d);
        if (ov > bv || (ov == bv && oi < bi)) { bv = ov; bi = oi; }
    }
    if (lane == 0) tab2[seg] = (unsigned char)bi;
}

// ------------------------------------------------------- per-row argmax
__device__ __forceinline__ int argmax48(const float4* __restrict__ row) {
    float best = -__builtin_inff();
    int bi = 0;
#pragma unroll
    for (int i = 0; i < 12; ++i) {
        float4 v = row[i];
        if (v.x > best) { best = v.x; bi = 4 * i + 0; }
        if (v.y > best) { best = v.y; bi = 4 * i + 1; }
        if (v.z > best) { best = v.z; bi = 4 * i + 2; }
        if (v.w > best) { best = v.w; bi = 4 * i + 3; }
    }
    return bi;
}

// ----------- fused level kernel: atomic scatter (blocks < nblkA) + row argmax
__global__ void level_kernel(const float* __restrict__ fsrc,
                             const int* __restrict__ parent,
                             float* __restrict__ fdst,
                             unsigned char* __restrict__ tabsrc,
                             int nrows, int nblkA) {
    if ((int)blockIdx.x < nblkA) {
        int e = blockIdx.x * 256 + threadIdx.x;
        if (e < nrows * C) {
            unsigned r = (unsigned)e / C;
            unsigned c = (unsigned)e - r * C;
            atomicAdd(&fdst[(unsigned)parent[r] * C + c], fsrc[e]);
        }
    } else {
        int r = (blockIdx.x - nblkA) * 256 + threadIdx.x;
        if (r < nrows) tabsrc[r] = (unsigned char)argmax48((const float4*)fsrc + r * 12);
    }
}

// --------------- final gather: tab2/3/4 lookups + LDS-cached tab5
__global__ void final_kernel(const unsigned char* __restrict__ tab2,
                             const unsigned char* __restrict__ tab3,
                             const unsigned char* __restrict__ tab4,
                             const float4* __restrict__ f5,
                             const int4* __restrict__ idx2,
                             const int4* __restrict__ idx3,
                             const int4* __restrict__ idx4,
                             const int4* __restrict__ idx5,
                             int4* __restrict__ out) {
    __shared__ unsigned char t5[N5];
    int tid = threadIdx.x;
    t5[tid] = (unsigned char)argmax48(f5 + tid * 12);   // 256 threads = 256 rows
    __syncthreads();
    const int NQ = N1 / 4;
    int t = blockIdx.x * blockDim.x + tid;
    if (t >= NQ) return;
    int4 a = idx2[t], b = idx3[t], c = idx4[t], d = idx5[t];
    out[t] = make_int4(tab2[a.x], tab2[a.y], tab2[a.z], tab2[a.w]);
    out[NQ + t] = make_int4(tab3[b.x], tab3[b.y], tab3[b.z], tab3[b.w]);
    out[2 * NQ + t] = make_int4(tab4[c.x], tab4[c.y], tab4[c.z], tab4[c.w]);
    out[3 * NQ + t] = make_int4(t5[d.x], t5[d.y], t5[d.z], t5[d.w]);
}

extern "C" void kernel_launch(void* const* d_in, const int* in_sizes, int n_in,
                              void* d_out, int out_size, void* d_ws, size_t ws_size,
                              hipStream_t stream) {
    const float* slabel  = (const float*)d_in[0];
    const int* parent2   = (const int*)d_in[1];
    const int* parent3   = (const int*)d_in[2];
    const int* parent4   = (const int*)d_in[3];
    const int* parent5   = (const int*)d_in[4];
    const int* idx2      = (const int*)d_in[5];
    const int* idx3      = (const int*)d_in[6];
    const int* idx4      = (const int*)d_in[7];
    const int* idx5      = (const int*)d_in[8];
    int* out = (int*)d_out;   // JAX argmax output dtype is int32

    // ---- workspace layout (dwords) ----
    // [f3 | f4 | f5 | cnt2 | rowid2(N2*CAP) | tab2|tab3|tab4 (bytes)]
    float* f3 = (float*)d_ws;
    float* f4 = f3 + (size_t)N3 * C;
    float* f5 = f4 + (size_t)N4 * C;
    int* cnt2 = (int*)(f5 + (size_t)N5 * C);
    int* rowid2 = cnt2 + N2;
    unsigned char* tab2 = (unsigned char*)(rowid2 + (size_t)N2 * CAP);
    unsigned char* tab3 = tab2 + N2;
    unsigned char* tab4 = tab3 + N3;

    // 1) zero cnt2 via fast fill (512 KB); f3/f4/f5 zeroed inside reorder
    hipMemsetAsync(cnt2, 0, (size_t)N2 * 4, stream);

    // 2) fused: table zeroing (876 blocks) + direct-slot sort (3907 blocks)
    reorder_zero_kernel<<<ZBLK + (N1 + 255) / 256, 256, 0, stream>>>(
        parent2, cnt2, rowid2, (float4*)d_ws);

    // 3) fused: 5-rows-per-load segment-sum + argmax->tab2 + atomic f3
    segsum_fused_kernel<<<N2 / 4, 256, 0, stream>>>(
        slabel, rowid2, cnt2, parent3, f3, tab2, N2);

    // 4) level 3: f3->f4 atomics (3072 blocks) + tab3 argmax (64 blocks)
    level_kernel<<<3072 + 64, 256, 0, stream>>>(f3, parent4, f4, tab3, N3, 3072);

    // 5) level 4: f4->f5 atomics (384 blocks) + tab4 argmax (8 blocks)
    level_kernel<<<384 + 8, 256, 0, stream>>>(f4, parent5, f5, tab4, N4, 384);

    // 6) final: tab lookups + per-block LDS tab5
    final_kernel<<<(N1 / 4 + 255) / 256, 256, 0, stream>>>(
        tab2, tab3, tab4, (const float4*)f5,
        (const int4*)idx2, (const int4*)idx3, (const int4*)idx4, (const int4*)idx5,
        (int4*)out);
}